// Round 1
// baseline (386.877 us; speedup 1.0000x reference)
//
#include <hip/hip_runtime.h>
#include <math.h>

#define BN 4096   // batch
#define DN 16384  // features per row

// Host-side python computes these in double, then JAX demotes to f32 at use.
static constexpr double kWFirstD = 2.0 - 10.0 * (2.0 / 49.0);          // 78/49
static constexpr double kWLastD  = 2.0 - kWFirstD;                      // 20/49
static constexpr double kStepD   = (kWFirstD - kWLastD) / (BN - 1);

// ---------------------------------------------------------------------------
// Kernel 1: per-row squared-sum -> difficulty[row] = 0.5*loss + 0.5*||g||2
// One block per row, 256 threads, float4 loads (16 B/lane, fully coalesced).
// Memory-bound: 256 MiB streamed once. Arithmetic order UNCHANGED from the
// absmax==0.0 baseline. Extras (both negligible): reset the completion
// counter for kernel 2's fused mean, and mirror difficulty into an aligned
// workspace copy so kernel 2 can load it with float4 (out+1 is only 4B
// aligned).
// ---------------------------------------------------------------------------
__global__ __launch_bounds__(256)
void sspl_rownorm(const float* __restrict__ loss,
                  const float* __restrict__ grads,
                  float* __restrict__ diff_out,
                  float* __restrict__ diff_aligned,
                  unsigned int* __restrict__ counter) {
    const int row = blockIdx.x;
    if (row == 0 && threadIdx.x == 0) *counter = 0u;   // ws is poisoned each iter
    const float4* __restrict__ g =
        reinterpret_cast<const float4*>(grads + (size_t)row * DN);
    float s = 0.0f;
#pragma unroll
    for (int it = 0; it < DN / 4 / 256; ++it) {   // 16 iterations
        const float4 v = g[it * 256 + threadIdx.x];
        s += v.x * v.x + v.y * v.y + v.z * v.z + v.w * v.w;
    }
#pragma unroll
    for (int off = 32; off > 0; off >>= 1) s += __shfl_down(s, off, 64);
    __shared__ float wave_part[4];
    const int lane = threadIdx.x & 63;
    const int wave = threadIdx.x >> 6;
    if (lane == 0) wave_part[wave] = s;
    __syncthreads();
    if (threadIdx.x == 0) {
        const float tot = wave_part[0] + wave_part[1] + wave_part[2] + wave_part[3];
        const float d = 0.5f * loss[row] + 0.5f * sqrtf(tot);
        diff_out[row] = d;
        diff_aligned[row] = d;
    }
}

// ---------------------------------------------------------------------------
// Kernel 2 (fused rank + mean):
// rank(j) = #{d_i < d_j} + #{d_i == d_j && i < j}   (== stable argsort pos).
// 256 blocks x 256 threads: block b handles j in [16b, 16b+16); 16 threads
// cooperate per j. Scan is now float4 over LDS (ds_read_b128): thread `seg`
// reads sd[64t + 4seg .. +3] for t=0..63 — 16 distinct 16B slots per 16-lane
// group (conflict-free), broadcast across the 4 jj-groups of the wave.
// cnt is integer-identical to the scalar version -> contrib bit-identical.
//
// The deterministic mean is fused via the last-block-done pattern:
// every wave fences (release, agent scope — flushes this XCD's L2 so other
// XCDs can see contrib), thread 0 bumps the counter, and the last block
// acquires (invalidate L1/L2) then replays the OLD sspl_mean code verbatim —
// same summation order, bit-exact out[0], deterministic regardless of which
// block finishes last.
// ---------------------------------------------------------------------------
__global__ __launch_bounds__(256)
void sspl_rank_mean(const float* __restrict__ loss,
                    const float* __restrict__ diff,      // aligned ws copy
                    float* __restrict__ contrib,
                    unsigned int* __restrict__ counter,
                    float* __restrict__ out0) {
    __shared__ alignas(16) float sd[BN];  // 16 KiB
    {
        const float4* __restrict__ d4 = reinterpret_cast<const float4*>(diff);
        float4* __restrict__ s4 = reinterpret_cast<float4*>(sd);
#pragma unroll
        for (int it = 0; it < BN / 4 / 256; ++it)   // 4 iterations
            s4[it * 256 + threadIdx.x] = d4[it * 256 + threadIdx.x];
    }
    __syncthreads();

    const int jj  = threadIdx.x >> 4;   // local j (0..15)
    const int seg = threadIdx.x & 15;   // segment of the i-scan (0..15)
    const int j   = (blockIdx.x << 4) + jj;
    const float dj = sd[j];

    int cnt = 0;
#pragma unroll 8
    for (int t = 0; t < 64; ++t) {
        const int i0 = (t << 6) | (seg << 2);       // 64t + 4seg
        const float4 dv = *reinterpret_cast<const float4*>(&sd[i0]);
        cnt += (dv.x < dj || (dv.x == dj && (i0 + 0) < j)) ? 1 : 0;
        cnt += (dv.y < dj || (dv.y == dj && (i0 + 1) < j)) ? 1 : 0;
        cnt += (dv.z < dj || (dv.z == dj && (i0 + 2) < j)) ? 1 : 0;
        cnt += (dv.w < dj || (dv.w == dj && (i0 + 3) < j)) ? 1 : 0;
    }
    // reduce across the 16 cooperating lanes (contiguous within one wave)
#pragma unroll
    for (int off = 8; off > 0; off >>= 1) cnt += __shfl_down(cnt, off, 16);

    if (seg == 0) {
        const float w = (float)kWFirstD - (float)kStepD * (float)cnt;
        contrib[j] = loss[j] * w;
    }

    // ---- fused deterministic mean (replaces the old 3rd kernel) ----
    __threadfence();        // release: every wave flushes its contrib stores
    __syncthreads();
    __shared__ int is_last;
    if (threadIdx.x == 0)
        is_last = (atomicAdd(counter, 1u) == (unsigned)gridDim.x - 1u);
    __syncthreads();
    if (is_last) {
        __threadfence();    // acquire: invalidate stale L1/L2 lines
        float s = 0.0f;
#pragma unroll
        for (int it = 0; it < BN / 256; ++it) s += contrib[it * 256 + threadIdx.x];
#pragma unroll
        for (int off = 32; off > 0; off >>= 1) s += __shfl_down(s, off, 64);
        __shared__ float wave_part[4];
        const int lane = threadIdx.x & 63;
        const int wave = threadIdx.x >> 6;
        if (lane == 0) wave_part[wave] = s;
        __syncthreads();
        if (threadIdx.x == 0) {
            out0[0] = (wave_part[0] + wave_part[1] + wave_part[2] + wave_part[3]) *
                      (1.0f / BN);
        }
    }
}

extern "C" void kernel_launch(void* const* d_in, const int* in_sizes, int n_in,
                              void* d_out, int out_size, void* d_ws, size_t ws_size,
                              hipStream_t stream) {
    const float* loss  = (const float*)d_in[0];   // [4096]
    const float* grads = (const float*)d_in[1];   // [4096 x 16384]
    float* out = (float*)d_out;                   // [0]=weighted_loss, [1..4096]=difficulty
    float* ws  = (float*)d_ws;
    float* contrib      = ws;                     // 4096 floats
    float* diff_aligned = ws + BN;                // 4096 floats, 16B aligned
    unsigned int* counter = (unsigned int*)(ws + 2 * BN);

    sspl_rownorm<<<BN, 256, 0, stream>>>(loss, grads, out + 1, diff_aligned, counter);
    sspl_rank_mean<<<BN / 16, 256, 0, stream>>>(loss, diff_aligned, contrib, counter, out);
}

// Round 2
// 370.632 us; speedup vs baseline: 1.0438x; 1.0438x over previous
//
#include <hip/hip_runtime.h>
#include <math.h>

#define BN 4096   // batch
#define DN 16384  // features per row

// Host-side python computes these in double, then JAX demotes to f32 at use.
static constexpr double kWFirstD = 2.0 - 10.0 * (2.0 / 49.0);          // 78/49
static constexpr double kWLastD  = 2.0 - kWFirstD;                      // 20/49
static constexpr double kStepD   = (kWFirstD - kWLastD) / (BN - 1);

// ---------------------------------------------------------------------------
// Kernel 1: per-row squared-sum -> difficulty[row] = 0.5*loss + 0.5*||g||2
// One block per row, 256 threads, float4 loads (16 B/lane, fully coalesced).
// Memory-bound: 256 MiB streamed once at the read ceiling. Arithmetic order
// UNCHANGED from the absmax==0.0 baseline. Also mirrors difficulty into a
// 16B-aligned workspace copy so kernel 2 can fill LDS with float4 (out+1 is
// only 4B-aligned).
// NOTE (R1 lesson): do NOT fuse the downstream mean via last-block-done —
// per-block device-scope __threadfence (cross-XCD L2 writeback) costs more
// than the ~2us dispatch it saves (+9us measured regression).
// ---------------------------------------------------------------------------
__global__ __launch_bounds__(256)
void sspl_rownorm(const float* __restrict__ loss,
                  const float* __restrict__ grads,
                  float* __restrict__ diff_out,
                  float* __restrict__ diff_aligned) {
    const int row = blockIdx.x;
    const float4* __restrict__ g =
        reinterpret_cast<const float4*>(grads + (size_t)row * DN);
    float s = 0.0f;
#pragma unroll
    for (int it = 0; it < DN / 4 / 256; ++it) {   // 16 iterations
        const float4 v = g[it * 256 + threadIdx.x];
        s += v.x * v.x + v.y * v.y + v.z * v.z + v.w * v.w;
    }
#pragma unroll
    for (int off = 32; off > 0; off >>= 1) s += __shfl_down(s, off, 64);
    __shared__ float wave_part[4];
    const int lane = threadIdx.x & 63;
    const int wave = threadIdx.x >> 6;
    if (lane == 0) wave_part[wave] = s;
    __syncthreads();
    if (threadIdx.x == 0) {
        const float tot = wave_part[0] + wave_part[1] + wave_part[2] + wave_part[3];
        const float d = 0.5f * loss[row] + 0.5f * sqrtf(tot);
        diff_out[row] = d;
        diff_aligned[row] = d;
    }
}

// ---------------------------------------------------------------------------
// Kernel 2: stable-sort rank of each difficulty + weighted contribution.
// rank(j) = #{d_i < d_j} + #{d_i == d_j && i < j}   (== stable argsort pos).
// 256 blocks x 256 threads: block b handles j in [16b, 16b+16); 16 threads
// cooperate per j. Scan is float4 over LDS (ds_read_b128): thread `seg`
// reads sd[64t + 4seg .. +3] for t=0..63 — 16 distinct 16B slots per 16-lane
// group (conflict-free), broadcast across the 4 jj-groups of the wave.
// cnt is integer-identical to the scalar version -> contrib bit-identical.
// ---------------------------------------------------------------------------
__global__ __launch_bounds__(256)
void sspl_rank(const float* __restrict__ loss,
               const float* __restrict__ diff,      // 16B-aligned ws copy
               float* __restrict__ contrib) {
    __shared__ alignas(16) float sd[BN];  // 16 KiB
    {
        const float4* __restrict__ d4 = reinterpret_cast<const float4*>(diff);
        float4* __restrict__ s4 = reinterpret_cast<float4*>(sd);
#pragma unroll
        for (int it = 0; it < BN / 4 / 256; ++it)   // 4 iterations
            s4[it * 256 + threadIdx.x] = d4[it * 256 + threadIdx.x];
    }
    __syncthreads();

    const int jj  = threadIdx.x >> 4;   // local j (0..15)
    const int seg = threadIdx.x & 15;   // segment of the i-scan (0..15)
    const int j   = (blockIdx.x << 4) + jj;
    const float dj = sd[j];

    int cnt = 0;
#pragma unroll 8
    for (int t = 0; t < 64; ++t) {
        const int i0 = (t << 6) | (seg << 2);       // 64t + 4seg
        const float4 dv = *reinterpret_cast<const float4*>(&sd[i0]);
        cnt += (dv.x < dj || (dv.x == dj && (i0 + 0) < j)) ? 1 : 0;
        cnt += (dv.y < dj || (dv.y == dj && (i0 + 1) < j)) ? 1 : 0;
        cnt += (dv.z < dj || (dv.z == dj && (i0 + 2) < j)) ? 1 : 0;
        cnt += (dv.w < dj || (dv.w == dj && (i0 + 3) < j)) ? 1 : 0;
    }
    // reduce across the 16 cooperating lanes (contiguous within one wave)
#pragma unroll
    for (int off = 8; off > 0; off >>= 1) cnt += __shfl_down(cnt, off, 16);

    if (seg == 0) {
        const float w = (float)kWFirstD - (float)kStepD * (float)cnt;
        contrib[j] = loss[j] * w;
    }
}

// ---------------------------------------------------------------------------
// Kernel 3: deterministic mean of the 4096 contributions -> d_out[0].
// Launch-latency dominated (~2us); cheaper than any fence-based fusion (R1).
// ---------------------------------------------------------------------------
__global__ __launch_bounds__(256)
void sspl_mean(const float* __restrict__ contrib, float* __restrict__ out0) {
    float s = 0.0f;
#pragma unroll
    for (int it = 0; it < BN / 256; ++it) s += contrib[it * 256 + threadIdx.x];
#pragma unroll
    for (int off = 32; off > 0; off >>= 1) s += __shfl_down(s, off, 64);
    __shared__ float wave_part[4];
    const int lane = threadIdx.x & 63;
    const int wave = threadIdx.x >> 6;
    if (lane == 0) wave_part[wave] = s;
    __syncthreads();
    if (threadIdx.x == 0) {
        out0[0] = (wave_part[0] + wave_part[1] + wave_part[2] + wave_part[3]) *
                  (1.0f / BN);
    }
}

extern "C" void kernel_launch(void* const* d_in, const int* in_sizes, int n_in,
                              void* d_out, int out_size, void* d_ws, size_t ws_size,
                              hipStream_t stream) {
    const float* loss  = (const float*)d_in[0];   // [4096]
    const float* grads = (const float*)d_in[1];   // [4096 x 16384]
    float* out = (float*)d_out;                   // [0]=weighted_loss, [1..4096]=difficulty
    float* ws  = (float*)d_ws;
    float* contrib      = ws;                     // 4096 floats
    float* diff_aligned = ws + BN;                // 4096 floats, 16B aligned

    sspl_rownorm<<<BN, 256, 0, stream>>>(loss, grads, out + 1, diff_aligned);
    sspl_rank<<<BN / 16, 256, 0, stream>>>(loss, diff_aligned, contrib);
    sspl_mean<<<1, 256, 0, stream>>>(contrib, out);
}